// Round 6
// baseline (408.455 us; speedup 1.0000x reference)
//
#include <hip/hip_runtime.h>

// Problem: B=65536 rows, DIM=256, K=1024 codewords.
// out layout (fp32): [0,16777216) quantize | [16777216] diff | [16777217,+65536) indices
#define NROWSQ   65536
#define NDIM     256
#define NCB      1024
#define DIFF_OFF 16777216
#define IDX_OFF  16777217

// bf16 phase-1 margin on 10-bit-quantized shifted scores (~7 sigma)
#define MARGIN_A 0.35f
// fp32 phase-2 margin -> below this, numpy-mimic decides.
#define MARGIN_B 1.5e-3f
// positivity shift: score = dot - 0.5||e||^2 + 384 in [~114, ~406] (provably >0)
#define SCORE_SHIFT 384.0f

typedef __attribute__((ext_vector_type(8))) short s16x8;
typedef __attribute__((ext_vector_type(4))) float f32x4;

__device__ __forceinline__ unsigned short f2bf(float f) {
  union { float f; unsigned u; } v; v.f = f;
  return (unsigned short)((v.u + 0x7FFFu + ((v.u >> 16) & 1u)) >> 16);  // RNE
}

__device__ __forceinline__ void top2_update(float& v1, int& i1, float& v2, int& i2,
                                            float v, int col) {
  if (v > v1 || (v == v1 && col < i1)) { v2 = v1; i2 = i1; v1 = v; i1 = col; }
  else if (v > v2 || (v == v2 && col < i2)) { v2 = v; i2 = col; }
}
__device__ __forceinline__ void top2_merge(float& v1, int& i1, float& v2, int& i2,
                                           float ov1, int oi1, float ov2, int oi2) {
  if (ov1 > v1 || (ov1 == v1 && oi1 < i1)) {
    float nv2 = v1; int ni2 = i1;
    if (ov2 > nv2 || (ov2 == nv2 && oi2 < ni2)) { nv2 = ov2; ni2 = oi2; }
    v1 = ov1; i1 = oi1; v2 = nv2; i2 = ni2;
  } else if (ov1 > v2 || (ov1 == v2 && oi1 < i2)) {
    v2 = ov1; i2 = oi1;
  }
}

// numpy pairwise_sum emulation for a contiguous 128-block (8 accumulators).
__device__ __forceinline__ float np_pairwise128(const float* p) {
  float r0 = p[0], r1 = p[1], r2 = p[2], r3 = p[3];
  float r4 = p[4], r5 = p[5], r6 = p[6], r7 = p[7];
  for (int i = 8; i < 128; i += 8) {
    r0 += p[i];     r1 += p[i + 1]; r2 += p[i + 2]; r3 += p[i + 3];
    r4 += p[i + 4]; r5 += p[i + 5]; r6 += p[i + 6]; r7 += p[i + 7];
  }
  return ((r0 + r1) + (r2 + r3)) + ((r4 + r5) + (r6 + r7));
}

// ---------------- k0: fused prep --------------------------------------------
// grid 68: blocks 0..63 transpose E -> embT(fp32)/cbT(bf16); 64..67 esq arrays.
__global__ void k0_prep(const float* __restrict__ E, float* __restrict__ embT,
                        unsigned short* __restrict__ cbT, float* __restrict__ esq32,
                        float* __restrict__ nesq, float* __restrict__ esqr,
                        int* __restrict__ cntA, int* __restrict__ cntB) {
  const int t = threadIdx.x;
  if (blockIdx.x < 64) {
    __shared__ float T[64][65];
    const int kbase = (blockIdx.x & 15) * 64;
    const int dbase = (blockIdx.x >> 4) * 64;
    #pragma unroll
    for (int i = 0; i < 4; ++i) {
      const int cid = i * 256 + t;
      const int dl = cid >> 4, kc = cid & 15;
      const float4 v = *(const float4*)(E + (size_t)(dbase + dl) * NCB + kbase + kc * 4);
      T[dl][kc * 4 + 0] = v.x; T[dl][kc * 4 + 1] = v.y;
      T[dl][kc * 4 + 2] = v.z; T[dl][kc * 4 + 3] = v.w;
    }
    __syncthreads();
    #pragma unroll
    for (int i = 0; i < 4; ++i) {
      const int cid = i * 256 + t;
      const int kl = cid >> 4, dc = cid & 15;
      float4 v;
      v.x = T[dc * 4 + 0][kl]; v.y = T[dc * 4 + 1][kl];
      v.z = T[dc * 4 + 2][kl]; v.w = T[dc * 4 + 3][kl];
      *(float4*)(embT + (size_t)(kbase + kl) * NDIM + dbase + dc * 4) = v;
      ushort4 b;
      b.x = f2bf(v.x); b.y = f2bf(v.y); b.z = f2bf(v.z); b.w = f2bf(v.w);
      *(ushort4*)(cbT + (size_t)(kbase + kl) * NDIM + dbase + dc * 4) = b;
    }
  } else {
    const int k = (blockIdx.x - 64) * 256 + t;
    if (blockIdx.x == 64 && t == 0) { *cntA = 0; *cntB = 0; }
    double s = 0.0;
    float sr = 0.f;
    for (int d = 0; d < NDIM; ++d) {
      const float v = E[d * NCB + k];
      s += (double)v * (double)v;
      const float p = v * v;   // fp32 rounded product
      sr = sr + p;             // numpy axis-0 reduce: sequential fp32
    }
    esq32[k] = (float)(0.5 * s);
    nesq[k] = SCORE_SHIFT - (float)(0.5 * s);  // MFMA C-init value
    esqr[k] = sr;
  }
}

// ---------------- k1: bf16 MFMA scores, column-split 2-way -------------------
// grid 1024: rowtile = bid>>1 (128 rows), half = bid&1 (512 cols, 8 N-tiles).
// LDS: XOR-swizzled fragment-ordered B tile (32 KB, conflict-free write+read).
// Pipeline: prefetch next tile into VGPRs during compute of current tile.
// MFMA acc C-initialized with (384 - 0.5||e||^2) -> epilogue is pack+3 max/min.
__global__ void k1_scores(
    const float* __restrict__ X, const unsigned short* __restrict__ cbT,
    const float* __restrict__ nesq, int2* __restrict__ part1) {
  __shared__ uint4 Bs[2048];       // 32 KB: chunk (c,d8) at swizzled addr16
  __shared__ float esq_l[512];     // negated shifted esq for this half
  const int t = threadIdx.x;
  const int lane = t & 63, w = t >> 6;
  const int l15 = lane & 15, quad = lane >> 4;
  const int half = blockIdx.x & 1;
  const int rowbase = (blockIdx.x >> 1) * 128;
  const int colbase = half * 512;

  {
    const float2 e2 = *(const float2*)(nesq + colbase + t * 2);
    *(float2*)(esq_l + t * 2) = e2;
  }

  // staging roles (thread-based): c = i*8 + trow, d8 = t&31 -> ks,quad
  const int trow = t >> 5;
  const int tks = (t >> 2) & 7, tquad = t & 3;
  const uint4* cb4 = (const uint4*)cbT;   // 32 chunks per codebook row

  // A fragments: lane holds A[m=l15][k=quad*8+j] per (m-tile, ks).
  s16x8 afrag[2][8];
  #pragma unroll
  for (int m = 0; m < 2; ++m) {
    const float* xr = X + (size_t)(rowbase + w * 32 + m * 16 + l15) * NDIM;
    #pragma unroll
    for (int ks = 0; ks < 8; ++ks) {
      const float4 xa = *(const float4*)(xr + ks * 32 + quad * 8);
      const float4 xb = *(const float4*)(xr + ks * 32 + quad * 8 + 4);
      s16x8 a;
      a[0] = (short)f2bf(xa.x); a[1] = (short)f2bf(xa.y);
      a[2] = (short)f2bf(xa.z); a[3] = (short)f2bf(xa.w);
      a[4] = (short)f2bf(xb.x); a[5] = (short)f2bf(xb.y);
      a[6] = (short)f2bf(xb.z); a[7] = (short)f2bf(xb.w);
      afrag[m][ks] = a;
    }
  }

  int key1[2][4], key2[2][4];
  #pragma unroll
  for (int m = 0; m < 2; ++m)
    #pragma unroll
    for (int r = 0; r < 4; ++r) { key1[m][r] = 0; key2[m][r] = 0; }

  // prefetch tile 0
  uint4 p[8];
  #pragma unroll
  for (int i = 0; i < 8; ++i)
    p[i] = cb4[(size_t)(colbase + i * 8 + trow) * 32 + (t & 31)];

  for (int nt = 0; nt < 8; ++nt) {
    __syncthreads();   // all waves done reading previous tile
    // write prefetched tile to swizzled LDS (conflict-free: 8 bank-groups x 4)
    #pragma unroll
    for (int i = 0; i < 8; ++i) {
      const int c = i * 8 + trow;
      const int a16 = ((c >> 4) * 8 + tks) * 64 + tquad * 16 + ((c & 15) ^ tks);
      Bs[a16] = p[i];
    }
    __syncthreads();
    // issue next tile's global loads now; they complete during compute
    if (nt < 7) {
      #pragma unroll
      for (int i = 0; i < 8; ++i)
        p[i] = cb4[(size_t)(colbase + (nt + 1) * 64 + i * 8 + trow) * 32 + (t & 31)];
    }

    // C-init accumulators with negated shifted esq (score falls out of MFMA)
    f32x4 acc[2][4];
    #pragma unroll
    for (int s = 0; s < 4; ++s) {
      const float e = esq_l[nt * 64 + s * 16 + l15];
      acc[0][s] = (f32x4){e, e, e, e};
      acc[1][s] = (f32x4){e, e, e, e};
    }

    #pragma unroll
    for (int ks = 0; ks < 8; ++ks) {
      #pragma unroll
      for (int s = 0; s < 4; ++s) {
        const s16x8 b = *(const s16x8*)((const char*)Bs +
            ((s * 8 + ks) * 1024 + quad * 256 + ((l15 ^ ks) * 16)));
        acc[0][s] = __builtin_amdgcn_mfma_f32_16x16x32_bf16(afrag[0][ks], b, acc[0][s], 0, 0, 0);
        acc[1][s] = __builtin_amdgcn_mfma_f32_16x16x32_bf16(afrag[1][ks], b, acc[1][s], 0, 0, 0);
      }
    }

    // epilogue: key = (score_bits & ~1023) | (1023-col); 4 ops per update
    #pragma unroll
    for (int s = 0; s < 4; ++s) {
      const int suffix = 1023 - (colbase + nt * 64 + s * 16 + l15);
      #pragma unroll
      for (int m = 0; m < 2; ++m)
        #pragma unroll
        for (int r = 0; r < 4; ++r) {
          const int key = (__float_as_int(acc[m][s][r]) & 0xFFFFFC00) | suffix;
          key2[m][r] = max(key2[m][r], min(key1[m][r], key));
          key1[m][r] = max(key1[m][r], key);
        }
    }
  }

  #pragma unroll
  for (int mask = 1; mask <= 8; mask <<= 1) {
    #pragma unroll
    for (int m = 0; m < 2; ++m)
      #pragma unroll
      for (int r = 0; r < 4; ++r) {
        const int ok1 = __shfl_xor(key1[m][r], mask);
        const int ok2 = __shfl_xor(key2[m][r], mask);
        const int n1 = max(key1[m][r], ok1);
        const int n2 = max(min(key1[m][r], ok1), max(key2[m][r], ok2));
        key1[m][r] = n1; key2[m][r] = n2;
      }
  }

  if (l15 == 0) {
    #pragma unroll
    for (int m = 0; m < 2; ++m)
      #pragma unroll
      for (int r = 0; r < 4; ++r) {
        const int grow = rowbase + w * 32 + m * 16 + quad * 4 + r;
        part1[half * NROWSQ + grow] = make_int2(key1[m][r], key2[m][r]);
      }
  }
}

// ---------------- k1m: merge halves, write idx, build listA, zero diff -------
__global__ void k1m_merge(const int2* __restrict__ part1, float* __restrict__ outIdx,
                          int* __restrict__ cntA, int* __restrict__ listA,
                          float* __restrict__ outDiff) {
  const int row = blockIdx.x * 256 + threadIdx.x;
  if (row == 0) *outDiff = 0.f;
  const int2 a = part1[row];
  const int2 b = part1[NROWSQ + row];
  const int k1 = max(a.x, b.x);
  const int k2 = max(min(a.x, b.x), max(a.y, b.y));
  outIdx[row] = (float)(1023 - (k1 & 1023));
  const float g1 = __int_as_float(k1 & 0xFFFFFC00);
  const float g2 = __int_as_float(k2 & 0xFFFFFC00);
  if (g1 - g2 < MARGIN_A) {
    const int p = atomicAdd(cntA, 1);
    listA[p] = row;
  }
}

// ---------------- k2a: fp32 recompute for contested rows, column-split -------
__global__ __launch_bounds__(256) void k2a_refine(
    const float* __restrict__ X, const float* __restrict__ E,
    const float* __restrict__ esq, const int* __restrict__ cntA,
    const int* __restrict__ listA, float4* __restrict__ part2) {
  __shared__ float Xs[8][NDIM];
  __shared__ float rv1[4][8], rv2[4][8];
  __shared__ int   ri1[4][8], ri2[4][8];
  const int t = threadIdx.x;
  const int lane = t & 63, w = t >> 6;
  const int half = blockIdx.x & 1;
  const int bstride = gridDim.x >> 1;
  const int cnt = *cntA;
  const int k0 = half * 512 + t * 2;
  for (int base = (blockIdx.x >> 1) * 8; base < cnt; base += bstride * 8) {
    const int nrows = min(8, cnt - base);
    __syncthreads();
    for (int r = 0; r < 8; ++r) {
      const int rid = listA[base + min(r, nrows - 1)];
      Xs[r][t] = X[(size_t)rid * NDIM + t];
    }
    __syncthreads();

    float acc[8][2];
    #pragma unroll
    for (int r = 0; r < 8; ++r) { acc[r][0] = 0.f; acc[r][1] = 0.f; }

    for (int d = 0; d < NDIM; ++d) {
      const float2 e = *(const float2*)(E + d * NCB + k0);
      #pragma unroll
      for (int r = 0; r < 8; ++r) {
        const float x = Xs[r][d];
        acc[r][0] += x * e.x; acc[r][1] += x * e.y;
      }
    }
    const float eq0 = esq[k0], eq1 = esq[k0 + 1];

    #pragma unroll
    for (int r = 0; r < 8; ++r) {
      float bv1 = -3.4e38f, bv2 = -3.4e38f; int bi1 = 0x7fffffff, bi2 = 0x7fffffff;
      top2_update(bv1, bi1, bv2, bi2, acc[r][0] - eq0, k0);
      top2_update(bv1, bi1, bv2, bi2, acc[r][1] - eq1, k0 + 1);
      #pragma unroll
      for (int mask = 1; mask < 64; mask <<= 1) {
        const float ov1 = __shfl_xor(bv1, mask); const int oi1 = __shfl_xor(bi1, mask);
        const float ov2 = __shfl_xor(bv2, mask); const int oi2 = __shfl_xor(bi2, mask);
        top2_merge(bv1, bi1, bv2, bi2, ov1, oi1, ov2, oi2);
      }
      if (lane == 0) { rv1[w][r] = bv1; ri1[w][r] = bi1; rv2[w][r] = bv2; ri2[w][r] = bi2; }
    }
    __syncthreads();
    if (t < nrows) {
      const int r = t;
      float fv1 = rv1[0][r], fv2 = rv2[0][r]; int fi1 = ri1[0][r], fi2 = ri2[0][r];
      for (int ww = 1; ww < 4; ++ww)
        top2_merge(fv1, fi1, fv2, fi2, rv1[ww][r], ri1[ww][r], rv2[ww][r], ri2[ww][r]);
      part2[half * NROWSQ + base + r] = make_float4(fv1, (float)fi1, fv2, (float)fi2);
    }
    __syncthreads();
  }
}

// ---------------- k2m: merge k2a halves, write idx, build listB --------------
__global__ void k2m_merge(const float4* __restrict__ part2, const int* __restrict__ cntA,
                          const int* __restrict__ listA, float* __restrict__ outIdx,
                          int* __restrict__ cntB, int* __restrict__ listB) {
  const int cnt = *cntA;
  for (int j = blockIdx.x * 256 + threadIdx.x; j < cnt; j += gridDim.x * 256) {
    const float4 a = part2[j];
    const float4 b = part2[NROWSQ + j];
    float v1 = a.x, v2 = a.z; int i1 = (int)a.y, i2 = (int)a.w;
    top2_merge(v1, i1, v2, i2, b.x, (int)b.y, b.z, (int)b.w);
    const int rid = listA[j];
    outIdx[rid] = (float)i1;
    if (v1 - v2 < MARGIN_B) { const int p = atomicAdd(cntB, 1); listB[p] = rid; }
  }
}

// ---------------- k2b: reference-mimicking fp32 for near-tied rows -----------
__global__ __launch_bounds__(256) void k2b_mimic(
    const float* __restrict__ X, const float* __restrict__ embT,
    const float* __restrict__ esqr, const int* __restrict__ cntB,
    const int* __restrict__ listB, float* __restrict__ outIdx) {
  __shared__ float Xr[NDIM];
  __shared__ float Psq[NDIM];
  __shared__ float rv[256];
  __shared__ int ri[256];
  const int t = threadIdx.x;
  const int cnt = *cntB;
  for (int j = blockIdx.x; j < cnt; j += gridDim.x) {
    const int rid = listB[j];
    __syncthreads();
    {
      const float x = X[(size_t)rid * NDIM + t];
      Xr[t] = x;
      Psq[t] = x * x;
    }
    __syncthreads();
    const float x_sq = np_pairwise128(Psq) + np_pairwise128(Psq + 128);

    float best = 3.4e38f; int bidx = 0x7fffffff;
    #pragma unroll
    for (int c = 0; c < 4; ++c) {
      const int k = t + c * 256;
      const float* er = embT + (size_t)k * NDIM;
      float acc = 0.f;
      #pragma unroll 8
      for (int dq = 0; dq < 64; ++dq) {
        const float4 e = *(const float4*)(er + dq * 4);
        const float4 x = *(const float4*)(Xr + dq * 4);
        acc = fmaf(x.x, e.x, acc);   // strict d-order chain (OpenBLAS mimic)
        acc = fmaf(x.y, e.y, acc);
        acc = fmaf(x.z, e.z, acc);
        acc = fmaf(x.w, e.w, acc);
      }
      const float dist = (x_sq - 2.0f * acc) + esqr[k];
      if (dist < best || (dist == best && k < bidx)) { best = dist; bidx = k; }
    }
    rv[t] = best; ri[t] = bidx;
    __syncthreads();
    for (int off = 128; off > 0; off >>= 1) {
      if (t < off) {
        if (rv[t + off] < rv[t] || (rv[t + off] == rv[t] && ri[t + off] < ri[t])) {
          rv[t] = rv[t + off]; ri[t] = ri[t + off];
        }
      }
      __syncthreads();
    }
    if (t == 0) outIdx[rid] = (float)ri[0];
  }
}

// ---------------- k4: gather codeword, write quantize, diff atomic -----------
__global__ __launch_bounds__(256) void k4_outputs(
    const float* __restrict__ X, const float* __restrict__ embT,
    const float* __restrict__ idxF, float* __restrict__ outQ,
    float* __restrict__ outDiff) {
  const int t = threadIdx.x;
  const int lane = t & 63, w = t >> 6;
  const int W = blockIdx.x * 4 + w;
  float s = 0.f;
  #pragma unroll
  for (int i = 0; i < 8; ++i) {
    const int r = W + i * 8192;
    const int idx = (int)idxF[r];
    const float4 q = *(const float4*)(embT + idx * NDIM + lane * 4);
    const float4 x = *(const float4*)(X + (size_t)r * NDIM + lane * 4);
    *(float4*)(outQ + (size_t)r * NDIM + lane * 4) = q;
    const float dx = q.x - x.x, dy = q.y - x.y, dz = q.z - x.z, dw = q.w - x.w;
    s += dx * dx + dy * dy + dz * dz + dw * dw;
  }
  #pragma unroll
  for (int mask = 1; mask < 64; mask <<= 1) s += __shfl_xor(s, mask);
  __shared__ float bs[4];
  if (lane == 0) bs[w] = s;
  __syncthreads();
  if (t == 0)
    atomicAdd(outDiff, (bs[0] + bs[1] + bs[2] + bs[3]) * (1.0f / 16777216.0f));
}

// ---------------- launch -----------------------------------------------------
extern "C" void kernel_launch(void* const* d_in, const int* in_sizes, int n_in,
                              void* d_out, int out_size, void* d_ws, size_t ws_size,
                              hipStream_t stream) {
  const float* X = (const float*)d_in[0];     // [65536, 256]
  const float* E = (const float*)d_in[1];     // [256, 1024]
  float* out = (float*)d_out;

  char* ws = (char*)d_ws;                     // ~5.1 MB used
  unsigned short* cbT = (unsigned short*)(ws + 0x000000);  // bf16 [1024][256] 512KB
  float*  embT  = (float*) (ws + 0x080000);   // fp32 [1024][256] 1MB
  float*  esq32 = (float*) (ws + 0x180000);   // 4KB (hi-prec half-norm)
  float*  nesq  = (float*) (ws + 0x181000);   // 4KB (negated shifted, k1 C-init)
  float*  esqr  = (float*) (ws + 0x182000);   // 4KB (ref-mimic e_sq)
  int* cntA  = (int*)(ws + 0x183000);
  int* cntB  = (int*)(ws + 0x183004);
  int* listA = (int*)(ws + 0x183100);         // 256KB
  int* listB = (int*)(ws + 0x1C3100);         // 256KB
  int2*   part1 = (int2*)  (ws + 0x203100);   // 2 x 65536 x 8B = 1MB
  float4* part2 = (float4*)(ws + 0x303100);   // 2 x 65536 x 16B = 2MB

  float* outQ    = out;
  float* outDiff = out + DIFF_OFF;
  float* outIdx  = out + IDX_OFF;

  k0_prep<<<dim3(68), dim3(256), 0, stream>>>(E, embT, cbT, esq32, nesq, esqr, cntA, cntB);
  k1_scores<<<dim3(1024), dim3(256), 0, stream>>>(X, cbT, nesq, part1);
  k1m_merge<<<dim3(256), dim3(256), 0, stream>>>(part1, outIdx, cntA, listA, outDiff);
  k2a_refine<<<dim3(1024), dim3(256), 0, stream>>>(X, E, esq32, cntA, listA, part2);
  k2m_merge<<<dim3(64), dim3(256), 0, stream>>>(part2, cntA, listA, outIdx, cntB, listB);
  k2b_mimic<<<dim3(64), dim3(256), 0, stream>>>(X, embT, esqr, cntB, listB, outIdx);
  k4_outputs<<<dim3(2048), dim3(256), 0, stream>>>(X, embT, outIdx, outQ, outDiff);
}

// Round 9
// 402.973 us; speedup vs baseline: 1.0136x; 1.0136x over previous
//
#include <hip/hip_runtime.h>

// Problem: B=65536 rows, DIM=256, K=1024 codewords.
// out layout (fp32): [0,16777216) quantize | [16777216] diff | [16777217,+65536) indices
#define NROWSQ   65536
#define NDIM     256
#define NCB      1024
#define DIFF_OFF 16777216
#define IDX_OFF  16777217

// bf16 phase-1 margin on 10-bit-chopped shifted scores. Score-diff sigma ~0.036
// + 0.062 chop; 0.35 ~ 8 sigma. Empirically passed rounds 2-6.
#define MARGIN_A 0.35f
// fp32 phase-2 margin -> below this, numpy-mimic decides.
#define MARGIN_B 1.5e-3f
// positivity shift: score = dot - 0.5||e||^2 + 384 in [~114, ~406] (provably >0)
#define SCORE_SHIFT 384.0f

typedef __attribute__((ext_vector_type(8))) short s16x8;
typedef __attribute__((ext_vector_type(4))) float f32x4;

__device__ __forceinline__ unsigned short f2bf(float f) {
  union { float f; unsigned u; } v; v.f = f;
  return (unsigned short)((v.u + 0x7FFFu + ((v.u >> 16) & 1u)) >> 16);  // RNE
}

__device__ __forceinline__ void top2_update(float& v1, int& i1, float& v2, int& i2,
                                            float v, int col) {
  if (v > v1 || (v == v1 && col < i1)) { v2 = v1; i2 = i1; v1 = v; i1 = col; }
  else if (v > v2 || (v == v2 && col < i2)) { v2 = v; i2 = col; }
}
__device__ __forceinline__ void top2_merge(float& v1, int& i1, float& v2, int& i2,
                                           float ov1, int oi1, float ov2, int oi2) {
  if (ov1 > v1 || (ov1 == v1 && oi1 < i1)) {
    float nv2 = v1; int ni2 = i1;
    if (ov2 > nv2 || (ov2 == nv2 && oi2 < ni2)) { nv2 = ov2; ni2 = oi2; }
    v1 = ov1; i1 = oi1; v2 = nv2; i2 = ni2;
  } else if (ov1 > v2 || (ov1 == v2 && oi1 < i2)) {
    v2 = ov1; i2 = oi1;
  }
}

// numpy pairwise_sum emulation for a contiguous 128-block (8 accumulators).
__device__ __forceinline__ float np_pairwise128(const float* p) {
  float r0 = p[0], r1 = p[1], r2 = p[2], r3 = p[3];
  float r4 = p[4], r5 = p[5], r6 = p[6], r7 = p[7];
  for (int i = 8; i < 128; i += 8) {
    r0 += p[i];     r1 += p[i + 1]; r2 += p[i + 2]; r3 += p[i + 3];
    r4 += p[i + 4]; r5 += p[i + 5]; r6 += p[i + 6]; r7 += p[i + 7];
  }
  return ((r0 + r1) + (r2 + r3)) + ((r4 + r5) + (r6 + r7));
}

// ---------------- k0: fused prep --------------------------------------------
// grid 68: blocks 0..63 transpose E -> embT(fp32)/cbT(bf16); 64..67 esq arrays.
__global__ void k0_prep(const float* __restrict__ E, float* __restrict__ embT,
                        unsigned short* __restrict__ cbT, float* __restrict__ esq32,
                        float* __restrict__ nesq, float* __restrict__ esqr,
                        int* __restrict__ cntA, int* __restrict__ cntB) {
  const int t = threadIdx.x;
  if (blockIdx.x < 64) {
    __shared__ float T[64][65];
    const int kbase = (blockIdx.x & 15) * 64;
    const int dbase = (blockIdx.x >> 4) * 64;
    #pragma unroll
    for (int i = 0; i < 4; ++i) {
      const int cid = i * 256 + t;
      const int dl = cid >> 4, kc = cid & 15;
      const float4 v = *(const float4*)(E + (size_t)(dbase + dl) * NCB + kbase + kc * 4);
      T[dl][kc * 4 + 0] = v.x; T[dl][kc * 4 + 1] = v.y;
      T[dl][kc * 4 + 2] = v.z; T[dl][kc * 4 + 3] = v.w;
    }
    __syncthreads();
    #pragma unroll
    for (int i = 0; i < 4; ++i) {
      const int cid = i * 256 + t;
      const int kl = cid >> 4, dc = cid & 15;
      float4 v;
      v.x = T[dc * 4 + 0][kl]; v.y = T[dc * 4 + 1][kl];
      v.z = T[dc * 4 + 2][kl]; v.w = T[dc * 4 + 3][kl];
      *(float4*)(embT + (size_t)(kbase + kl) * NDIM + dbase + dc * 4) = v;
      ushort4 b;
      b.x = f2bf(v.x); b.y = f2bf(v.y); b.z = f2bf(v.z); b.w = f2bf(v.w);
      *(ushort4*)(cbT + (size_t)(kbase + kl) * NDIM + dbase + dc * 4) = b;
    }
  } else {
    const int k = (blockIdx.x - 64) * 256 + t;
    if (blockIdx.x == 64 && t == 0) { *cntA = 0; *cntB = 0; }
    double s = 0.0;
    float sr = 0.f;
    for (int d = 0; d < NDIM; ++d) {
      const float v = E[d * NCB + k];
      s += (double)v * (double)v;
      const float p = v * v;   // fp32 rounded product
      sr = sr + p;             // numpy axis-0 reduce: sequential fp32
    }
    esq32[k] = (float)(0.5 * s);
    nesq[k] = SCORE_SHIFT - (float)(0.5 * s);  // MFMA C-init value
    esqr[k] = sr;
  }
}

// ---------------- k1: bf16 MFMA scores, register-prefetch + ds_write ---------
// grid 1024: rowtile = bid>>1 (128 rows), half = bid&1 (512 cols, 8 N-tiles).
// LDS slot map (16B units): slot(c,d8) = ((c>>4)*8 + (d8>>2))*64 + (c&15)*4
//   + (d8&3). Bijective; b128 writes span all 8 bank-groups (lane>>5)*4 +
//   (lane&3); b128 fragment reads span (l15&1)*4 + quad -> both 8-phase
//   conflict-free. Staging path: coalesced global -> regs -> ds_write (the
//   global_load_lds path of r7/r8 produced timing-dependent corruption).
__global__ __launch_bounds__(256, 3) void k1_scores(
    const float* __restrict__ X, const unsigned short* __restrict__ cbT,
    const float* __restrict__ nesq, int2* __restrict__ part1) {
  __shared__ __align__(16) uint4 Bs[2048];   // 32 KB
  __shared__ float esq_l[512];
  const int t = threadIdx.x;
  const int lane = t & 63, w = t >> 6;
  const int l15 = lane & 15, quad = lane >> 4;
  const int half = blockIdx.x & 1;
  const int rowbase = (blockIdx.x >> 1) * 128;
  const int colbase = half * 512;

  {
    const float2 e2 = *(const float2*)(nesq + colbase + t * 2);
    *(float2*)(esq_l + t * 2) = e2;
  }

  // staging roles: thread t covers chunks (c = i*8 + trow, d8 = t&31)
  const int trow = t >> 5;
  const int d8 = t & 31;
  const uint4* cb4 = (const uint4*)cbT;   // 32 x 16B chunks per codebook row

  // A fragments: lane holds A[m=l15][k=quad*8+j] per (m-tile, ks).
  s16x8 afrag[2][8];
  #pragma unroll
  for (int m = 0; m < 2; ++m) {
    const float* xr = X + (size_t)(rowbase + w * 32 + m * 16 + l15) * NDIM;
    #pragma unroll
    for (int ks = 0; ks < 8; ++ks) {
      const float4 xa = *(const float4*)(xr + ks * 32 + quad * 8);
      const float4 xb = *(const float4*)(xr + ks * 32 + quad * 8 + 4);
      s16x8 a;
      a[0] = (short)f2bf(xa.x); a[1] = (short)f2bf(xa.y);
      a[2] = (short)f2bf(xa.z); a[3] = (short)f2bf(xa.w);
      a[4] = (short)f2bf(xb.x); a[5] = (short)f2bf(xb.y);
      a[6] = (short)f2bf(xb.z); a[7] = (short)f2bf(xb.w);
      afrag[m][ks] = a;
    }
  }

  int key1[2][4], key2[2][4];
  #pragma unroll
  for (int m = 0; m < 2; ++m)
    #pragma unroll
    for (int r = 0; r < 4; ++r) { key1[m][r] = 0; key2[m][r] = 0; }

  // prefetch tile 0 into registers (coalesced: 32 consecutive lanes = 1 row)
  uint4 p[8];
  #pragma unroll
  for (int i = 0; i < 8; ++i)
    p[i] = cb4[(size_t)(colbase + i * 8 + trow) * 32 + d8];

  for (int nt = 0; nt < 8; ++nt) {
    __syncthreads();   // all waves done reading previous tile
    // conflict-free swizzled ds_write of the prefetched tile
    #pragma unroll
    for (int i = 0; i < 8; ++i) {
      const int c = i * 8 + trow;
      Bs[((c >> 4) * 8 + (d8 >> 2)) * 64 + (c & 15) * 4 + (d8 & 3)] = p[i];
    }
    __syncthreads();
    // issue next tile's global loads now; MFMA burst below hides their latency
    if (nt < 7) {
      #pragma unroll
      for (int i = 0; i < 8; ++i)
        p[i] = cb4[(size_t)(colbase + (nt + 1) * 64 + i * 8 + trow) * 32 + d8];
    }

    // C-init accumulators with (384 - 0.5||e||^2): score falls out of MFMA
    f32x4 acc[2][4];
    #pragma unroll
    for (int s = 0; s < 4; ++s) {
      const float e = esq_l[nt * 64 + s * 16 + l15];
      acc[0][s] = (f32x4){e, e, e, e};
      acc[1][s] = (f32x4){e, e, e, e};
    }

    #pragma unroll
    for (int ks = 0; ks < 8; ++ks) {
      #pragma unroll
      for (int s = 0; s < 4; ++s) {
        const s16x8 b = *(const s16x8*)&Bs[(s * 8 + ks) * 64 + l15 * 4 + quad];
        acc[0][s] = __builtin_amdgcn_mfma_f32_16x16x32_bf16(afrag[0][ks], b, acc[0][s], 0, 0, 0);
        acc[1][s] = __builtin_amdgcn_mfma_f32_16x16x32_bf16(afrag[1][ks], b, acc[1][s], 0, 0, 0);
      }
    }

    // epilogue: key = (score_bits & ~1023) | (1023-col); branchless top-2
    #pragma unroll
    for (int s = 0; s < 4; ++s) {
      const int suffix = 1023 - (colbase + nt * 64 + s * 16 + l15);
      #pragma unroll
      for (int m = 0; m < 2; ++m)
        #pragma unroll
        for (int r = 0; r < 4; ++r) {
          const int key = (__float_as_int(acc[m][s][r]) & 0xFFFFFC00) | suffix;
          key2[m][r] = max(key2[m][r], min(key1[m][r], key));
          key1[m][r] = max(key1[m][r], key);
        }
    }
  }

  #pragma unroll
  for (int mask = 1; mask <= 8; mask <<= 1) {
    #pragma unroll
    for (int m = 0; m < 2; ++m)
      #pragma unroll
      for (int r = 0; r < 4; ++r) {
        const int ok1 = __shfl_xor(key1[m][r], mask);
        const int ok2 = __shfl_xor(key2[m][r], mask);
        const int n1 = max(key1[m][r], ok1);
        const int n2 = max(min(key1[m][r], ok1), max(key2[m][r], ok2));
        key1[m][r] = n1; key2[m][r] = n2;
      }
  }

  if (l15 == 0) {
    #pragma unroll
    for (int m = 0; m < 2; ++m)
      #pragma unroll
      for (int r = 0; r < 4; ++r) {
        const int grow = rowbase + w * 32 + m * 16 + quad * 4 + r;
        part1[half * NROWSQ + grow] = make_int2(key1[m][r], key2[m][r]);
      }
  }
}

// ---------------- k1m: merge halves, write idx, build listA, zero diff -------
__global__ void k1m_merge(const int2* __restrict__ part1, float* __restrict__ outIdx,
                          int* __restrict__ cntA, int* __restrict__ listA,
                          float* __restrict__ outDiff) {
  const int row = blockIdx.x * 256 + threadIdx.x;
  if (row == 0) *outDiff = 0.f;
  const int2 a = part1[row];
  const int2 b = part1[NROWSQ + row];
  const int k1 = max(a.x, b.x);
  const int k2 = max(min(a.x, b.x), max(a.y, b.y));
  outIdx[row] = (float)(1023 - (k1 & 1023));
  const float g1 = __int_as_float(k1 & 0xFFFFFC00);
  const float g2 = __int_as_float(k2 & 0xFFFFFC00);
  if (g1 - g2 < MARGIN_A) {
    const int p = atomicAdd(cntA, 1);
    listA[p] = row;
  }
}

// ---------------- k2a: fp32 recompute for contested rows, column-split -------
// grid 1024: half = bid&1 (512 cols), 16 rows per E-stream.
#define K2A_R 16
__global__ __launch_bounds__(256) void k2a_refine(
    const float* __restrict__ X, const float* __restrict__ E,
    const float* __restrict__ esq, const int* __restrict__ cntA,
    const int* __restrict__ listA, float4* __restrict__ part2) {
  __shared__ float Xs[K2A_R][NDIM];
  __shared__ float rv1[4][K2A_R], rv2[4][K2A_R];
  __shared__ int   ri1[4][K2A_R], ri2[4][K2A_R];
  const int t = threadIdx.x;
  const int lane = t & 63, w = t >> 6;
  const int half = blockIdx.x & 1;
  const int bstride = gridDim.x >> 1;
  const int cnt = *cntA;
  const int k0 = half * 512 + t * 2;
  for (int base = (blockIdx.x >> 1) * K2A_R; base < cnt; base += bstride * K2A_R) {
    const int nrows = min(K2A_R, cnt - base);
    __syncthreads();
    for (int r = 0; r < K2A_R; ++r) {
      const int rid = listA[base + min(r, nrows - 1)];
      Xs[r][t] = X[(size_t)rid * NDIM + t];
    }
    __syncthreads();

    float acc[K2A_R][2];
    #pragma unroll
    for (int r = 0; r < K2A_R; ++r) { acc[r][0] = 0.f; acc[r][1] = 0.f; }

    for (int d = 0; d < NDIM; ++d) {
      const float2 e = *(const float2*)(E + d * NCB + k0);
      #pragma unroll
      for (int r = 0; r < K2A_R; ++r) {
        const float x = Xs[r][d];
        acc[r][0] += x * e.x; acc[r][1] += x * e.y;
      }
    }
    const float eq0 = esq[k0], eq1 = esq[k0 + 1];

    #pragma unroll
    for (int r = 0; r < K2A_R; ++r) {
      float bv1 = -3.4e38f, bv2 = -3.4e38f; int bi1 = 0x7fffffff, bi2 = 0x7fffffff;
      top2_update(bv1, bi1, bv2, bi2, acc[r][0] - eq0, k0);
      top2_update(bv1, bi1, bv2, bi2, acc[r][1] - eq1, k0 + 1);
      #pragma unroll
      for (int mask = 1; mask < 64; mask <<= 1) {
        const float ov1 = __shfl_xor(bv1, mask); const int oi1 = __shfl_xor(bi1, mask);
        const float ov2 = __shfl_xor(bv2, mask); const int oi2 = __shfl_xor(bi2, mask);
        top2_merge(bv1, bi1, bv2, bi2, ov1, oi1, ov2, oi2);
      }
      if (lane == 0) { rv1[w][r] = bv1; ri1[w][r] = bi1; rv2[w][r] = bv2; ri2[w][r] = bi2; }
    }
    __syncthreads();
    if (t < nrows) {
      const int r = t;
      float fv1 = rv1[0][r], fv2 = rv2[0][r]; int fi1 = ri1[0][r], fi2 = ri2[0][r];
      for (int ww = 1; ww < 4; ++ww)
        top2_merge(fv1, fi1, fv2, fi2, rv1[ww][r], ri1[ww][r], rv2[ww][r], ri2[ww][r]);
      part2[half * NROWSQ + base + r] = make_float4(fv1, (float)fi1, fv2, (float)fi2);
    }
    __syncthreads();
  }
}

// ---------------- k2m: merge k2a halves, write idx, build listB --------------
__global__ void k2m_merge(const float4* __restrict__ part2, const int* __restrict__ cntA,
                          const int* __restrict__ listA, float* __restrict__ outIdx,
                          int* __restrict__ cntB, int* __restrict__ listB) {
  const int cnt = *cntA;
  for (int j = blockIdx.x * 256 + threadIdx.x; j < cnt; j += gridDim.x * 256) {
    const float4 a = part2[j];
    const float4 b = part2[NROWSQ + j];
    float v1 = a.x, v2 = a.z; int i1 = (int)a.y, i2 = (int)a.w;
    top2_merge(v1, i1, v2, i2, b.x, (int)b.y, b.z, (int)b.w);
    const int rid = listA[j];
    outIdx[rid] = (float)i1;
    if (v1 - v2 < MARGIN_B) { const int p = atomicAdd(cntB, 1); listB[p] = rid; }
  }
}

// ---------------- k2b: reference-mimicking fp32 for near-tied rows -----------
__global__ __launch_bounds__(256) void k2b_mimic(
    const float* __restrict__ X, const float* __restrict__ embT,
    const float* __restrict__ esqr, const int* __restrict__ cntB,
    const int* __restrict__ listB, float* __restrict__ outIdx) {
  __shared__ float Xr[NDIM];
  __shared__ float Psq[NDIM];
  __shared__ float rv[256];
  __shared__ int ri[256];
  const int t = threadIdx.x;
  const int cnt = *cntB;
  for (int j = blockIdx.x; j < cnt; j += gridDim.x) {
    const int rid = listB[j];
    __syncthreads();
    {
      const float x = X[(size_t)rid * NDIM + t];
      Xr[t] = x;
      Psq[t] = x * x;
    }
    __syncthreads();
    const float x_sq = np_pairwise128(Psq) + np_pairwise128(Psq + 128);

    float best = 3.4e38f; int bidx = 0x7fffffff;
    #pragma unroll
    for (int c = 0; c < 4; ++c) {
      const int k = t + c * 256;
      const float* er = embT + (size_t)k * NDIM;
      float acc = 0.f;
      #pragma unroll 8
      for (int dq = 0; dq < 64; ++dq) {
        const float4 e = *(const float4*)(er + dq * 4);
        const float4 x = *(const float4*)(Xr + dq * 4);
        acc = fmaf(x.x, e.x, acc);   // strict d-order chain (OpenBLAS mimic)
        acc = fmaf(x.y, e.y, acc);
        acc = fmaf(x.z, e.z, acc);
        acc = fmaf(x.w, e.w, acc);
      }
      const float dist = (x_sq - 2.0f * acc) + esqr[k];
      if (dist < best || (dist == best && k < bidx)) { best = dist; bidx = k; }
    }
    rv[t] = best; ri[t] = bidx;
    __syncthreads();
    for (int off = 128; off > 0; off >>= 1) {
      if (t < off) {
        if (rv[t + off] < rv[t] || (rv[t + off] == rv[t] && ri[t + off] < ri[t])) {
          rv[t] = rv[t + off]; ri[t] = ri[t + off];
        }
      }
      __syncthreads();
    }
    if (t == 0) outIdx[rid] = (float)ri[0];
  }
}

// ---------------- k4: gather codeword, write quantize, diff atomic -----------
__global__ __launch_bounds__(256) void k4_outputs(
    const float* __restrict__ X, const float* __restrict__ embT,
    const float* __restrict__ idxF, float* __restrict__ outQ,
    float* __restrict__ outDiff) {
  const int t = threadIdx.x;
  const int lane = t & 63, w = t >> 6;
  const int W = blockIdx.x * 4 + w;
  float s = 0.f;
  #pragma unroll
  for (int i = 0; i < 8; ++i) {
    const int r = W + i * 8192;
    const int idx = (int)idxF[r];
    const float4 q = *(const float4*)(embT + idx * NDIM + lane * 4);
    const float4 x = *(const float4*)(X + (size_t)r * NDIM + lane * 4);
    *(float4*)(outQ + (size_t)r * NDIM + lane * 4) = q;
    const float dx = q.x - x.x, dy = q.y - x.y, dz = q.z - x.z, dw = q.w - x.w;
    s += dx * dx + dy * dy + dz * dz + dw * dw;
  }
  #pragma unroll
  for (int mask = 1; mask < 64; mask <<= 1) s += __shfl_xor(s, mask);
  __shared__ float bs[4];
  if (lane == 0) bs[w] = s;
  __syncthreads();
  if (t == 0)
    atomicAdd(outDiff, (bs[0] + bs[1] + bs[2] + bs[3]) * (1.0f / 16777216.0f));
}

// ---------------- launch -----------------------------------------------------
extern "C" void kernel_launch(void* const* d_in, const int* in_sizes, int n_in,
                              void* d_out, int out_size, void* d_ws, size_t ws_size,
                              hipStream_t stream) {
  const float* X = (const float*)d_in[0];     // [65536, 256]
  const float* E = (const float*)d_in[1];     // [256, 1024]
  float* out = (float*)d_out;

  char* ws = (char*)d_ws;                     // ~5.1 MB used
  unsigned short* cbT = (unsigned short*)(ws + 0x000000);  // bf16 [1024][256] 512KB
  float*  embT  = (float*) (ws + 0x080000);   // fp32 [1024][256] 1MB
  float*  esq32 = (float*) (ws + 0x180000);   // 4KB (hi-prec half-norm)
  float*  nesq  = (float*) (ws + 0x181000);   // 4KB (negated shifted, k1 C-init)
  float*  esqr  = (float*) (ws + 0x182000);   // 4KB (ref-mimic e_sq)
  int* cntA  = (int*)(ws + 0x183000);
  int* cntB  = (int*)(ws + 0x183004);
  int* listA = (int*)(ws + 0x183100);         // 256KB
  int* listB = (int*)(ws + 0x1C3100);         // 256KB
  int2*   part1 = (int2*)  (ws + 0x203100);   // 2 x 65536 x 8B = 1MB
  float4* part2 = (float4*)(ws + 0x303100);   // 2 x 65536 x 16B = 2MB

  float* outQ    = out;
  float* outDiff = out + DIFF_OFF;
  float* outIdx  = out + IDX_OFF;

  k0_prep<<<dim3(68), dim3(256), 0, stream>>>(E, embT, cbT, esq32, nesq, esqr, cntA, cntB);
  k1_scores<<<dim3(1024), dim3(256), 0, stream>>>(X, cbT, nesq, part1);
  k1m_merge<<<dim3(256), dim3(256), 0, stream>>>(part1, outIdx, cntA, listA, outDiff);
  k2a_refine<<<dim3(1024), dim3(256), 0, stream>>>(X, E, esq32, cntA, listA, part2);
  k2m_merge<<<dim3(64), dim3(256), 0, stream>>>(part2, cntA, listA, outIdx, cntB, listB);
  k2b_mimic<<<dim3(64), dim3(256), 0, stream>>>(X, embT, esqr, cntB, listB, outIdx);
  k4_outputs<<<dim3(2048), dim3(256), 0, stream>>>(X, embT, outIdx, outQ, outDiff);
}